// Round 1
// baseline (418.183 us; speedup 1.0000x reference)
//
#include <hip/hip_runtime.h>
#include <hip/hip_bf16.h>

typedef __attribute__((ext_vector_type(4))) float f32x4;
typedef __attribute__((ext_vector_type(8))) short s16x8;

#define NB_ 4
#define N_ 4096
#define FI_ 256
#define FO_ 128
#define NSTEP 128   // 4096 / 32

// pack two f32 -> one u32 of 2 bf16 (RNE), x in low half
__device__ inline unsigned pkbf(float a, float b) {
    __hip_bfloat162 t = __float22bfloat162_rn(make_float2(a, b));
    unsigned r; __builtin_memcpy(&r, &t, 4); return r;
}

// ---------------- K1: Wh = h @ W^T + Wb  (split-bf16 MFMA, err ~1e-5) ----
// wave w: row-tile rt=w>>1 (16 rows), col-half ch=w&1 (64 of 128 cols)
__global__ __launch_bounds__(256) void k1_wh(
    const float* __restrict__ h, const float* __restrict__ Ww,
    const float* __restrict__ Wb, float* __restrict__ Wh,
    __hip_bfloat16* __restrict__ WhT)
{
    const int tid = threadIdx.x;
    const int w = tid >> 6, l = tid & 63;
    const int rt = w >> 1, ch = w & 1;
    const int lr = l & 15, g = l >> 4;
    const int r0 = blockIdx.x * 32 + rt * 16;            // global row-tile base
    const float* hp = h + (size_t)(r0 + lr) * FI_ + g * 8;

    f32x4 acc[4] = {(f32x4)0.f, (f32x4)0.f, (f32x4)0.f, (f32x4)0.f};

    #pragma unroll
    for (int kt = 0; kt < 8; ++kt) {
        // A fragment: h[row=lr][k = kt*32 + g*8 + 0..7], hi/lo split
        f32x4 x0 = *(const f32x4*)(hp + kt * 32);
        f32x4 x1 = *(const f32x4*)(hp + kt * 32 + 4);
        float xx[8];
        #pragma unroll
        for (int t = 0; t < 4; ++t) { xx[t] = x0[t]; xx[t + 4] = x1[t]; }
        union { s16x8 v; unsigned u[4]; } ahi, alo;
        #pragma unroll
        for (int t = 0; t < 4; ++t) {
            float a0 = xx[2 * t], a1 = xx[2 * t + 1];
            unsigned uh = pkbf(a0, a1);
            ahi.u[t] = uh;
            float h0f = __uint_as_float(uh << 16);
            float h1f = __uint_as_float(uh & 0xffff0000u);
            alo.u[t] = pkbf(a0 - h0f, a1 - h1f);
        }
        #pragma unroll
        for (int c = 0; c < 4; ++c) {
            const float* wp = Ww + (size_t)(ch * 64 + c * 16 + lr) * FI_ + g * 8 + kt * 32;
            f32x4 b0 = *(const f32x4*)(wp);
            f32x4 b1 = *(const f32x4*)(wp + 4);
            float bb[8];
            #pragma unroll
            for (int t = 0; t < 4; ++t) { bb[t] = b0[t]; bb[t + 4] = b1[t]; }
            union { s16x8 v; unsigned u[4]; } bhi, blo;
            #pragma unroll
            for (int t = 0; t < 4; ++t) {
                float c0 = bb[2 * t], c1 = bb[2 * t + 1];
                unsigned uh = pkbf(c0, c1);
                bhi.u[t] = uh;
                float h0f = __uint_as_float(uh << 16);
                float h1f = __uint_as_float(uh & 0xffff0000u);
                blo.u[t] = pkbf(c0 - h0f, c1 - h1f);
            }
            acc[c] = __builtin_amdgcn_mfma_f32_16x16x32_bf16(ahi.v, bhi.v, acc[c], 0, 0, 0);
            acc[c] = __builtin_amdgcn_mfma_f32_16x16x32_bf16(alo.v, bhi.v, acc[c], 0, 0, 0);
            acc[c] = __builtin_amdgcn_mfma_f32_16x16x32_bf16(ahi.v, blo.v, acc[c], 0, 0, 0);
        }
    }

    // epilogue: C/D layout col=lane&15, row=(lane>>4)*4+reg  [verified m89]
    #pragma unroll
    for (int c = 0; c < 4; ++c) {
        int col = ch * 64 + c * 16 + lr;
        float wb = Wb[col];
        #pragma unroll
        for (int kk = 0; kk < 4; ++kk) {
            int grow = r0 + g * 4 + kk;
            float val = acc[c][kk] + wb;
            Wh[(size_t)grow * FO_ + col] = val;
            int bb = grow >> 12, nn = grow & 4095;
            WhT[((size_t)bb * FO_ + col) * N_ + nn] = __float2bfloat16(val);
        }
    }
}

// ---------------- K2: src/dst rows + per-batch max(dst+a_b) --------------
__global__ __launch_bounds__(256) void k2_vec(
    const float* __restrict__ Wh, const float* __restrict__ aw,
    const float* __restrict__ ab, float* __restrict__ srcv,
    float* __restrict__ dstbv, unsigned* __restrict__ maxenc)
{
    const int w = threadIdx.x >> 6, l = threadIdx.x & 63;
    const int r = blockIdx.x * 4 + w;                    // global row 0..16383
    const float2 wh = *(const float2*)(Wh + (size_t)r * FO_ + l * 2);
    const float2 as = *(const float2*)(aw + l * 2);
    const float2 ad = *(const float2*)(aw + FO_ + l * 2);
    float sp  = wh.x * as.x + wh.y * as.y;
    float dpv = wh.x * ad.x + wh.y * ad.y;
    #pragma unroll
    for (int off = 32; off >= 1; off >>= 1) {
        sp  += __shfl_xor(sp, off);
        dpv += __shfl_xor(dpv, off);
    }
    if (l == 0) {
        srcv[r] = sp;
        float db = dpv + ab[0];                          // dst_j + a_b folded
        dstbv[r] = db;
        unsigned u = __float_as_uint(db);
        u = (u & 0x80000000u) ? ~u : (u | 0x80000000u);  // order-preserving map
        atomicMax(&maxenc[r >> 12], u);
    }
}

// ---------------- K3: fused mask+LR+softmax+PV (rank-1 scores) -----------
// block = 4 waves; wave w: rt=w>>1 -> rows i_base+rt*16.. (+16), ch=w&1 -> 64 cols
__global__ __launch_bounds__(256) void k3_gat(
    const int* __restrict__ adj, const __hip_bfloat16* __restrict__ WhT,
    const float* __restrict__ srcv, const float* __restrict__ dstbv,
    const unsigned* __restrict__ maxenc, float* __restrict__ out)
{
    const int tid = threadIdx.x;
    const int w = tid >> 6, l = tid & 63;
    const int rt = w >> 1, ch = w & 1;
    const int lr = l & 15, g = l >> 4;
    const int blk = blockIdx.x;
    const int b = blk >> 7;                              // 128 blocks per batch
    const int i_base = (blk & 127) * 32 + rt * 16;       // row base within batch
    const int myrow = i_base + lr;                       // row this lane scores

    const float sm = srcv[b * N_ + myrow];
    const unsigned venc = maxenc[b];
    const unsigned ud = (venc & 0x80000000u) ? (venc ^ 0x80000000u) : ~venc;
    const float mdb = __uint_as_float(ud);               // max_j (dst_j + a_b)
    const float eub = sm + mdb;
    const float m = fmaxf(eub, 0.01f * eub);             // LR(upper bound) >= row max

    const int* adjp = adj + ((size_t)b * N_ + myrow) * N_ + g * 8;
    const float* dp = dstbv + (size_t)b * N_ + g * 8;
    const __hip_bfloat16* wp = WhT + ((size_t)b * FO_ + ch * 64 + lr) * N_ + g * 8;

    f32x4 acc0 = (f32x4)0.f, acc1 = (f32x4)0.f, acc2 = (f32x4)0.f,
          acc3 = (f32x4)0.f, accl = (f32x4)0.f;
    s16x8 ones;
    { union { s16x8 v; unsigned u[4]; } o;
      o.u[0] = o.u[1] = o.u[2] = o.u[3] = 0x3F803F80u; ones = o.v; }  // bf16 1.0

    // register double-buffer, distance-1 prefetch
    int4  ca0 = *(const int4*)(adjp), ca1 = *(const int4*)(adjp + 4);
    f32x4 cd0 = *(const f32x4*)(dp),  cd1 = *(const f32x4*)(dp + 4);
    s16x8 cw0 = *(const s16x8*)(wp);
    s16x8 cw1 = *(const s16x8*)(wp + 16 * N_);
    s16x8 cw2 = *(const s16x8*)(wp + 32 * N_);
    s16x8 cw3 = *(const s16x8*)(wp + 48 * N_);

    #pragma unroll 2
    for (int t = 0; t < NSTEP; ++t) {
        const int jn = (t + 1 < NSTEP ? t + 1 : t) * 32;
        int4  na0 = *(const int4*)(adjp + jn);
        int4  na1 = *(const int4*)(adjp + jn + 4);
        f32x4 nd0 = *(const f32x4*)(dp + jn);
        f32x4 nd1 = *(const f32x4*)(dp + jn + 4);
        s16x8 nw0 = *(const s16x8*)(wp + jn);
        s16x8 nw1 = *(const s16x8*)(wp + 16 * N_ + jn);
        s16x8 nw2 = *(const s16x8*)(wp + 32 * N_ + jn);
        s16x8 nw3 = *(const s16x8*)(wp + 48 * N_ + jn);

        float p[8];
        #pragma unroll
        for (int u2 = 0; u2 < 4; ++u2) {
            {
                float e = sm + cd0[u2];
                float lrv = fmaxf(e, 0.01f * e);         // LeakyReLU
                float pe = __expf(lrv - m);
                int av = (&ca0.x)[u2];
                p[u2] = av > 0 ? pe : 0.0f;
            }
            {
                float e = sm + cd1[u2];
                float lrv = fmaxf(e, 0.01f * e);
                float pe = __expf(lrv - m);
                int av = (&ca1.x)[u2];
                p[4 + u2] = av > 0 ? pe : 0.0f;
            }
        }
        union { s16x8 v; unsigned u[4]; } af;
        af.u[0] = pkbf(p[0], p[1]); af.u[1] = pkbf(p[2], p[3]);
        af.u[2] = pkbf(p[4], p[5]); af.u[3] = pkbf(p[6], p[7]);

        accl = __builtin_amdgcn_mfma_f32_16x16x32_bf16(af.v, ones, accl, 0, 0, 0);
        acc0 = __builtin_amdgcn_mfma_f32_16x16x32_bf16(af.v, cw0, acc0, 0, 0, 0);
        acc1 = __builtin_amdgcn_mfma_f32_16x16x32_bf16(af.v, cw1, acc1, 0, 0, 0);
        acc2 = __builtin_amdgcn_mfma_f32_16x16x32_bf16(af.v, cw2, acc2, 0, 0, 0);
        acc3 = __builtin_amdgcn_mfma_f32_16x16x32_bf16(af.v, cw3, acc3, 0, 0, 0);

        ca0 = na0; ca1 = na1; cd0 = nd0; cd1 = nd1;
        cw0 = nw0; cw1 = nw1; cw2 = nw2; cw3 = nw3;
    }

    // epilogue: accl[kk] is the row-sum for exactly the row this lane writes
    #pragma unroll
    for (int kk = 0; kk < 4; ++kk) {
        float inv = 1.0f / accl[kk];
        int row = i_base + g * 4 + kk;
        float* op = out + ((size_t)b * N_ + row) * FO_ + ch * 64 + lr;
        op[0]  = acc0[kk] * inv;
        op[16] = acc1[kk] * inv;
        op[32] = acc2[kk] * inv;
        op[48] = acc3[kk] * inv;
    }
}

extern "C" void kernel_launch(void* const* d_in, const int* in_sizes, int n_in,
                              void* d_out, int out_size, void* d_ws, size_t ws_size,
                              hipStream_t stream)
{
    const float* h  = (const float*)d_in[0];
    const int* adj  = (const int*)d_in[1];
    const float* Ww = (const float*)d_in[2];
    const float* Wb = (const float*)d_in[3];
    const float* aw = (const float*)d_in[4];
    const float* ab = (const float*)d_in[5];
    float* out = (float*)d_out;

    char* wsb = (char*)d_ws;
    float* Wh            = (float*)wsb;                               // 8 MB f32
    __hip_bfloat16* WhT  = (__hip_bfloat16*)(wsb + (8u << 20));       // 4 MB bf16 [b][o][n]
    float* srcv          = (float*)(wsb + (12u << 20));               // 64 KB
    float* dstbv         = (float*)(wsb + (12u << 20) + (64u << 10)); // 64 KB
    unsigned* maxenc     = (unsigned*)(wsb + (12u << 20) + (128u << 10)); // 16 B

    hipMemsetAsync(maxenc, 0, NB_ * sizeof(unsigned), stream);
    k1_wh<<<512, 256, 0, stream>>>(h, Ww, Wb, Wh, WhT);
    k2_vec<<<4096, 256, 0, stream>>>(Wh, aw, ab, srcv, dstbv, maxenc);
    k3_gat<<<512, 256, 0, stream>>>(adj, WhT, srcv, dstbv, maxenc, out);
}